// Round 7
// baseline (101.966 us; speedup 1.0000x reference)
//
#include <hip/hip_runtime.h>
#include <hip/hip_bf16.h>

// Problem constants
#define B_   8
#define L_   128
#define S_   160
#define H_   768
#define T_   16
#define CD_  50
#define WD_  100
#define NGATE 200   // 4*CD
#define NEGV (-1e30f)
#define FMAXV 3.402823466e+38f
#define NELEM (B_ * S_ * H_)      // 983040 floats in bert_emb

__device__ __forceinline__ float sigm(float x) {
    return __fdividef(1.f, 1.f + __expf(-x));
}
__device__ __forceinline__ float tanh_fast(float x) {
    float a = fabsf(x);
    float e = __expf(-2.f * a);
    float t = __fdividef(1.f - e, 1.f + e);
    return copysignf(t, x);
}

// shared-memory overlays (union via raw buffer; role is block-uniform)
struct WordS {
    int list[S_ + 4];
    int cnt;
    float red[256];
};
struct LstmS {                // 8 seqs per block
    float xs[T_][52][8];      // [t][k][s], k 50..51 zero pad   26624 B
    float hbuf[52][8];        // [k][s], rows 50/51 stay zero    1664 B
    float gbuf[8][NGATE];     //                                 6400 B
    int cid[8][T_];
    int slen[8];
    int smask[8];
};
#define SMEM_BYTES 35392      // >= max(sizeof(WordS), sizeof(LstmS)~35264)

// ---- weight row -> 13 named float4 registers (rows are 8B-aligned -> float2 loads) ----
#define LDW(W, p) { float2 a_ = *(const float2*)(p); float2 b_ = *(const float2*)((p) + 2); \
                    W = make_float4(a_.x, a_.y, b_.x, b_.y); }
#define LDW2(W, p) { float2 a_ = *(const float2*)(p); W = make_float4(a_.x, a_.y, 0.f, 0.f); }
// pin a float4 in VGPRs: volatile asm result cannot be rematerialized by the compiler
#define PIN4(v) asm volatile("" : "+v"((v).x), "+v"((v).y), "+v"((v).z), "+v"((v).w))

// one k-column of the 8-seq dot:  acc0..7 += W.C * v[k][0..7]
#define DOT8K(Wc, vk, k) { \
    const float4 vA_ = *(const float4*)((vk) + (k) * 8 + 0); \
    const float4 vB_ = *(const float4*)((vk) + (k) * 8 + 4); \
    acc0 = fmaf(Wc, vA_.x, acc0); acc1 = fmaf(Wc, vA_.y, acc1); \
    acc2 = fmaf(Wc, vA_.z, acc2); acc3 = fmaf(Wc, vA_.w, acc3); \
    acc4 = fmaf(Wc, vB_.x, acc4); acc5 = fmaf(Wc, vB_.y, acc5); \
    acc6 = fmaf(Wc, vB_.z, acc6); acc7 = fmaf(Wc, vB_.w, acc7); }
#define DOT8(W, vk, i) \
    DOT8K(W##i.x, vk, 4 * i + 0) DOT8K(W##i.y, vk, 4 * i + 1) \
    DOT8K(W##i.z, vk, 4 * i + 2) DOT8K(W##i.w, vk, 4 * i + 3)

// ---------------- word_reps maxpool + word_embed + cls (one word per call) ----------------
__device__ void kword_body(int bl, char* smem, const float* __restrict__ bert,
                           const int* __restrict__ p2w, const int* __restrict__ word_ids,
                           const float* __restrict__ word_table, float* __restrict__ out) {
    WordS& sh = *(WordS*)smem;
    int b = bl >> 7;
    int l = bl & 127;
    int tid = threadIdx.x;

    if (tid == 0) sh.cnt = 0;
    __syncthreads();
    if (tid < S_) {
        if (p2w[bl * S_ + tid]) {
            int p = atomicAdd(&sh.cnt, 1);   // order-independent: fmax is exact-commutative
            sh.list[p] = tid;
        }
    }
    __syncthreads();
    int n = sh.cnt;

    float a0, a1, a2;
    if (n > 0) {                             // n is block-uniform
        a0 = a1 = a2 = -FMAXV;
        if (tid < ((4 - (n & 3)) & 3)) sh.list[n + tid] = sh.list[0];   // pad (idempotent)
        __syncthreads();
        int n4 = (n + 3) & ~3;
        const float* bb = bert + (size_t)b * S_ * H_ + tid;
        for (int i = 0; i < n4; i += 4) {
            int s0 = sh.list[i], s1 = sh.list[i + 1], s2 = sh.list[i + 2], s3 = sh.list[i + 3];
            const float* r0 = bb + (size_t)s0 * H_;
            const float* r1 = bb + (size_t)s1 * H_;
            const float* r2 = bb + (size_t)s2 * H_;
            const float* r3 = bb + (size_t)s3 * H_;
            float v00 = r0[0],   v10 = r1[0],   v20 = r2[0],   v30 = r3[0];
            float v01 = r0[256], v11 = r1[256], v21 = r2[256], v31 = r3[256];
            float v02 = r0[512], v12 = r1[512], v22 = r2[512], v32 = r3[512];
            a0 = fmaxf(a0, fmaxf(fmaxf(v00, v10), fmaxf(v20, v30)));
            a1 = fmaxf(a1, fmaxf(fmaxf(v01, v11), fmaxf(v21, v31)));
            a2 = fmaxf(a2, fmaxf(fmaxf(v02, v12), fmaxf(v22, v32)));
        }
    } else {
        // all-masked word (probability ~2^-160; kept for strict correctness):
        // result = global min of bert_emb, computed locally.
        float m = FMAXV;
        const float4* x4 = (const float4*)bert;
        for (int i = tid; i < NELEM / 4; i += 256) {
            float4 v = x4[i];
            m = fminf(m, fminf(fminf(v.x, v.y), fminf(v.z, v.w)));
        }
        sh.red[tid] = m;
        __syncthreads();
        for (int o = 128; o > 0; o >>= 1) {
            if (tid < o) sh.red[tid] = fminf(sh.red[tid], sh.red[tid + o]);
            __syncthreads();
        }
        a0 = a1 = a2 = sh.red[0];
    }

    float* orow = out + (size_t)bl * 968;
    orow[tid] = a0; orow[tid + 256] = a1; orow[tid + 512] = a2;

    if (tid < WD_) {
        int wid = word_ids[bl];
        orow[768 + tid] = word_table[(size_t)wid * WD_ + tid];
    }
    if (l == 0) {   // cls embedding = bert_emb[b,0,:]
        const float* c = bert + (size_t)b * S_ * H_;
        float* co = out + (size_t)B_ * L_ * 968 + (size_t)b * H_;
        co[tid] = c[tid]; co[tid + 256] = c[tid + 256]; co[tid + 512] = c[tid + 512];
    }
}

// ---------------- fused BiLSTM unit (8 seqs): x-gates in-loop + recurrence + pool ----------------
// unit = dir*128 + grp; block owns 8 sequences of one direction for all 16 steps.
__device__ void lstm_body(int unit, char* smem,
                          const int* __restrict__ char_ids, const int* __restrict__ char_count,
                          const int* __restrict__ tok_mask, const float* __restrict__ char_table,
                          const float* __restrict__ w_ih_f, const float* __restrict__ w_hh_f,
                          const float* __restrict__ b_f,
                          const float* __restrict__ w_ih_b, const float* __restrict__ w_hh_b,
                          const float* __restrict__ b_b,
                          float* __restrict__ out) {
    LstmS& sh = *(LstmS*)smem;
    int dir = unit >> 7;
    int grp = unit & 127;
    int tid = threadIdx.x;

    if (tid < 128) {
        int s = tid >> 4, t = tid & 15;
        sh.cid[s][t] = char_ids[(grp * 8 + s) * T_ + t];
    } else if (tid < 136) {
        int s = tid - 128;
        int n = grp * 8 + s;
        int c = char_count[n];
        sh.slen[s] = (c > 0) ? c : 1;
        int mb = 0;
        for (int t = 0; t < T_; ++t) mb |= (tok_mask[n * T_ + t] != 0) << t;
        sh.smask[s] = mb;
    } else if (tid < 240) {    // zero hbuf: 104 threads x 4 floats = 416
        int i = (tid - 136) * 4;
        ((float*)sh.hbuf)[i] = 0.f; ((float*)sh.hbuf)[i + 1] = 0.f;
        ((float*)sh.hbuf)[i + 2] = 0.f; ((float*)sh.hbuf)[i + 3] = 0.f;
    }
    __syncthreads();   // slen/cid ready

    // stage x for all timesteps, [t][k][s] layout (reversed + zero-padded for backward)
    for (int idx = tid; idx < T_ * 52 * 8; idx += 256) {
        int t = idx / 416;
        int rem = idx - t * 416;
        int k = rem >> 3, s = rem & 7;
        int st = dir ? (sh.slen[s] - 1 - t) : t;
        float v = 0.f;
        if (k < CD_ && st >= 0) v = char_table[sh.cid[s][st] * CD_ + k];
        sh.xs[t][k][s] = v;
    }

    // weight rows resident in named registers, PINNED so the compiler cannot
    // rematerialize the loads inside the t-loop (R6: VGPR=64 proved it did).
    float4 ih0, ih1, ih2, ih3, ih4, ih5, ih6, ih7, ih8, ih9, ih10, ih11, ih12;
    float4 hh0, hh1, hh2, hh3, hh4, hh5, hh6, hh7, hh8, hh9, hh10, hh11, hh12;
    float bj = 0.f;
    if (tid < NGATE) {
        const float* wi = (dir ? w_ih_b : w_ih_f) + tid * CD_;
        const float* wh = (dir ? w_hh_b : w_hh_f) + tid * CD_;
        LDW(ih0,  wi +  0) LDW(ih1,  wi +  4) LDW(ih2,  wi +  8) LDW(ih3,  wi + 12)
        LDW(ih4,  wi + 16) LDW(ih5,  wi + 20) LDW(ih6,  wi + 24) LDW(ih7,  wi + 28)
        LDW(ih8,  wi + 32) LDW(ih9,  wi + 36) LDW(ih10, wi + 40) LDW(ih11, wi + 44)
        LDW2(ih12, wi + 48)
        LDW(hh0,  wh +  0) LDW(hh1,  wh +  4) LDW(hh2,  wh +  8) LDW(hh3,  wh + 12)
        LDW(hh4,  wh + 16) LDW(hh5,  wh + 20) LDW(hh6,  wh + 24) LDW(hh7,  wh + 28)
        LDW(hh8,  wh + 32) LDW(hh9,  wh + 36) LDW(hh10, wh + 40) LDW(hh11, wh + 44)
        LDW2(hh12, wh + 48)
        PIN4(ih0); PIN4(ih1); PIN4(ih2); PIN4(ih3); PIN4(ih4); PIN4(ih5); PIN4(ih6);
        PIN4(ih7); PIN4(ih8); PIN4(ih9); PIN4(ih10); PIN4(ih11); PIN4(ih12);
        PIN4(hh0); PIN4(hh1); PIN4(hh2); PIN4(hh3); PIN4(hh4); PIN4(hh5); PIN4(hh6);
        PIN4(hh7); PIN4(hh8); PIN4(hh9); PIN4(hh10); PIN4(hh11); PIN4(hh12);
        bj = (dir ? b_b : b_f)[tid];
    }
    __syncthreads();   // xs staged

    int cell = tid % CD_;
    int sb = tid / CD_;          // 0..3 for active threads
    float creg[2] = {0.f, 0.f};
    float mreg[2] = {NEGV, NEGV};

#pragma unroll 1
    for (int t = 0; t < T_; ++t) {
        if (tid < NGATE) {
            float acc0 = bj, acc1 = bj, acc2 = bj, acc3 = bj;
            float acc4 = bj, acc5 = bj, acc6 = bj, acc7 = bj;
            const float* xk = &sh.xs[t][0][0];
            DOT8(ih, xk, 0) DOT8(ih, xk, 1) DOT8(ih, xk, 2) DOT8(ih, xk, 3)
            DOT8(ih, xk, 4) DOT8(ih, xk, 5) DOT8(ih, xk, 6) DOT8(ih, xk, 7)
            DOT8(ih, xk, 8) DOT8(ih, xk, 9) DOT8(ih, xk, 10) DOT8(ih, xk, 11)
            DOT8(ih, xk, 12)
            const float* hk = &sh.hbuf[0][0];
            DOT8(hh, hk, 0) DOT8(hh, hk, 1) DOT8(hh, hk, 2) DOT8(hh, hk, 3)
            DOT8(hh, hk, 4) DOT8(hh, hk, 5) DOT8(hh, hk, 6) DOT8(hh, hk, 7)
            DOT8(hh, hk, 8) DOT8(hh, hk, 9) DOT8(hh, hk, 10) DOT8(hh, hk, 11)
            DOT8(hh, hk, 12)
            sh.gbuf[0][tid] = acc0; sh.gbuf[1][tid] = acc1;
            sh.gbuf[2][tid] = acc2; sh.gbuf[3][tid] = acc3;
            sh.gbuf[4][tid] = acc4; sh.gbuf[5][tid] = acc5;
            sh.gbuf[6][tid] = acc6; sh.gbuf[7][tid] = acc7;
        }
        __syncthreads();
        if (tid < NGATE) {
#pragma unroll
            for (int p = 0; p < 2; ++p) {
                int s = sb + 4 * p;
                float gi = sh.gbuf[s][cell];
                float gf = sh.gbuf[s][cell + CD_];
                float gg = sh.gbuf[s][cell + 2 * CD_];
                float go = sh.gbuf[s][cell + 3 * CD_];
                float cc = sigm(gf) * creg[p] + sigm(gi) * tanh_fast(gg);
                float h = sigm(go) * tanh_fast(cc);
                creg[p] = cc;
                sh.hbuf[cell][s] = h;
                int tt = dir ? (sh.slen[s] - 1 - t) : t;   // original time position
                if (tt >= 0 && ((sh.smask[s] >> tt) & 1)) mreg[p] = fmaxf(mreg[p], h);
            }
        }
        __syncthreads();
    }

    if (tid < NGATE) {
#pragma unroll
        for (int p = 0; p < 2; ++p) {
            int s = sb + 4 * p;
            float m = mreg[p];
            // backward half: masked positions at t >= len contribute h_bwd = 0
            if (dir && (sh.smask[s] >> sh.slen[s])) m = fmaxf(m, 0.f);
            if (m == NEGV) m = 0.f;
            out[(size_t)(grp * 8 + s) * 968 + 868 + dir * CD_ + cell] = m;
        }
    }
}

// ---------------- mega kernel: LSTM blocks first (long pole), words backfill ----------------
__global__ __launch_bounds__(256, 1) void kmega(
        const float* __restrict__ bert, const int* __restrict__ p2w,
        const int* __restrict__ word_ids, const int* __restrict__ char_ids,
        const int* __restrict__ char_count, const int* __restrict__ tok_mask,
        const float* __restrict__ word_table, const float* __restrict__ char_table,
        const float* __restrict__ w_ih_f, const float* __restrict__ w_hh_f,
        const float* __restrict__ b_f,
        const float* __restrict__ w_ih_b, const float* __restrict__ w_hh_b,
        const float* __restrict__ b_b,
        float* __restrict__ out) {
    __shared__ __align__(16) char smem[SMEM_BYTES];
    int bid = blockIdx.x;
    if (bid < 256) {
        lstm_body(bid, smem, char_ids, char_count, tok_mask, char_table,
                  w_ih_f, w_hh_f, b_f, w_ih_b, w_hh_b, b_b, out);
    } else {
        kword_body(bid - 256, smem, bert, p2w, word_ids, word_table, out);
    }
}

extern "C" void kernel_launch(void* const* d_in, const int* in_sizes, int n_in,
                              void* d_out, int out_size, void* d_ws, size_t ws_size,
                              hipStream_t stream) {
    const float* bert       = (const float*)d_in[0];
    const int*   p2w        = (const int*)d_in[1];
    const int*   word_ids   = (const int*)d_in[2];
    const int*   char_ids   = (const int*)d_in[3];
    const int*   char_count = (const int*)d_in[4];
    const int*   tok_mask   = (const int*)d_in[5];
    const float* word_table = (const float*)d_in[6];
    const float* char_table = (const float*)d_in[7];
    const float* w_ih_f = (const float*)d_in[8];
    const float* w_hh_f = (const float*)d_in[9];
    const float* b_f    = (const float*)d_in[10];
    const float* w_ih_b = (const float*)d_in[11];
    const float* w_hh_b = (const float*)d_in[12];
    const float* b_b    = (const float*)d_in[13];

    float* out = (float*)d_out;

    kmega<<<256 + B_ * L_, 256, 0, stream>>>(bert, p2w, word_ids, char_ids, char_count, tok_mask,
                                             word_table, char_table,
                                             w_ih_f, w_hh_f, b_f, w_ih_b, w_hh_b, b_b, out);
}

// Round 8
// 61.807 us; speedup vs baseline: 1.6497x; 1.6497x over previous
//
#include <hip/hip_runtime.h>

// Problem constants
#define B_   8
#define L_   128
#define S_   160
#define H_   768
#define T_   16
#define CD_  50
#define WD_  100
#define NGATE 200   // 4*CD
#define NEGV (-1e30f)
#define FMAXV 3.402823466e+38f
#define NELEM (B_ * S_ * H_)      // 983040 floats in bert_emb

typedef short  s16x8 __attribute__((ext_vector_type(8)));   // 8 bf16 in 4 VGPRs
typedef float  f32x4 __attribute__((ext_vector_type(4)));

__device__ __forceinline__ unsigned short f2bf(float f) {   // f32 -> bf16 RNE
    unsigned u = __float_as_uint(f);
    u = (u + 0x7FFFu + ((u >> 16) & 1u)) >> 16;
    return (unsigned short)u;
}
__device__ __forceinline__ float sigm(float x) {
    return __fdividef(1.f, 1.f + __expf(-x));
}
__device__ __forceinline__ float tanh_fast(float x) {
    float a = fabsf(x);
    float e = __expf(-2.f * a);
    float t = __fdividef(1.f - e, 1.f + e);
    return copysignf(t, x);
}

// ================== Kernel 1: MFMA BiLSTM (16 seqs/block, 128 blocks) ==================
// K-concat layout: k 0..63 = x (50 real), k 64..127 = h (50 real). 4 K-tiles of 32.
// A-frag LDS layout: unit idx (kt*4+kg)*16 + s holds 8 bf16 (k = kt*32+kg*8+[0..8)) of seq s.
// lane l reads unit (l>>4)*16 + (l&15)  [kg=l>>4, row s=l&15]  -> one ds_read_b128.
struct LstmS {
    s16x8 xbuf[2][128];   // double-buffered x A-frags (per-t)      4 KB
    s16x8 hbuf[128];      // h A-frags (K-tiles 2,3)                2 KB
    float gbuf[16][212];  // gates f32 [seq][gate], padded stride   13.6 KB
    int   cid[16][T_];
    int   slen[16], smask[16];
};

__global__ __launch_bounds__(256, 1) void klstm_mfma(
        const int* __restrict__ char_ids, const int* __restrict__ char_count,
        const int* __restrict__ tok_mask, const float* __restrict__ char_table,
        const float* __restrict__ w_ih_f, const float* __restrict__ w_hh_f,
        const float* __restrict__ b_f,
        const float* __restrict__ w_ih_b, const float* __restrict__ w_hh_b,
        const float* __restrict__ b_b,
        float* __restrict__ out) {
    __shared__ LstmS sh;
    const int unit = blockIdx.x;       // 0..127
    const int dir  = unit >> 6;
    const int grp  = unit & 63;        // 16 seqs: grp*16 ..
    const int tid  = threadIdx.x;
    const int lane = tid & 63;
    const int wv   = tid >> 6;

    // ---- prologue: metadata staging ----
    { int s = tid >> 4, t = tid & 15;
      sh.cid[s][t] = char_ids[(grp * 16 + s) * T_ + t]; }
    if (tid < 16) {
        int n = grp * 16 + tid;
        int c = char_count[n];
        sh.slen[tid] = (c > 0) ? c : 1;
        int mb = 0;
        for (int t = 0; t < T_; ++t) mb |= (tok_mask[n * T_ + t] != 0) << t;
        sh.smask[tid] = mb;
    }
    if (tid < 128) { s16x8 z = {0,0,0,0,0,0,0,0}; sh.hbuf[tid] = z; }

    // ---- B-fragments (weights) -> registers, once. wave wv owns N-tiles {wv, wv+4, wv+8 (,12)} ----
    const float* WI = dir ? w_ih_b : w_ih_f;
    const float* WH = dir ? w_hh_b : w_hh_f;
    const float* BV = dir ? b_b    : b_f;
    const int cnt = (wv == 0) ? 4 : 3;
    int   colj[4];
    float bv[4];
    s16x8 bf[4][4];
#pragma unroll
    for (int i = 0; i < 4; ++i) {
        int nt = (i < 3) ? (wv + 4 * i) : 12;
        int j  = nt * 16 + (lane & 15);
        bool jv = (i < cnt) && (j < NGATE);
        colj[i] = j;
        bv[i]   = jv ? BV[j] : 0.f;
        const float* wi = WI + j * CD_;
        const float* wh = WH + j * CD_;
#pragma unroll
        for (int kt = 0; kt < 4; ++kt) {
            int kst = kt * 32 + (lane >> 4) * 8;
            s16x8 fr = {0,0,0,0,0,0,0,0};
#pragma unroll
            for (int e = 0; e < 8; ++e) {
                int k = kst + e;
                float v = 0.f;
                if (jv) {
                    if (k < 64) { if (k < CD_) v = wi[k]; }
                    else        { int k2 = k - 64; if (k2 < CD_) v = wh[k2]; }
                }
                fr[e] = (short)f2bf(v);
            }
            bf[i][kt] = fr;
        }
    }
    __syncthreads();   // cid/slen ready for staging

    // ---- x stage: tid<128 each writes one A-frag unit (8 bf16) ----
#define STAGE_X(T, BUF) { \
    if (tid < 128) { \
        int s = tid & 15; \
        int g = tid >> 4;          /* 0..7 : kbase = g*8 covers k 0..63 */ \
        int kbase = g * 8; \
        int st = dir ? (sh.slen[s] - 1 - (T)) : (T); \
        s16x8 fr = {0,0,0,0,0,0,0,0}; \
        if (st >= 0) { \
            const float* row = char_table + sh.cid[s][st] * CD_; \
            _Pragma("unroll") \
            for (int e = 0; e < 8; ++e) { \
                int k = kbase + e; \
                if (k < CD_) fr[e] = (short)f2bf(row[k]); \
            } \
        } \
        sh.xbuf[BUF][g * 16 + s] = fr; \
    } }

    STAGE_X(0, 0)
    __syncthreads();   // xbuf[0] + hbuf(zero) ready

    const int laneofs = ((lane >> 4) << 4) + (lane & 15);   // kg*16 + s
    const int srow    = (lane >> 4) * 4;                    // D rows 4*(l>>4)+r

    // update-phase persistent state: thread owns units tid, tid+256, tid+512, tid+768 (<800)
    float cst0 = 0.f, cst1 = 0.f, cst2 = 0.f, cst3 = 0.f;
    float mr0 = NEGV, mr1 = NEGV, mr2 = NEGV, mr3 = NEGV;

#pragma unroll 1
    for (int t = 0; t < T_; ++t) {
        if (t + 1 < T_) STAGE_X(t + 1, (t + 1) & 1)

        // ---- MFMA phase: gates = [x|h] * W'^T + bias ----
        const s16x8* xb = sh.xbuf[t & 1];
        s16x8 a0 = xb[laneofs];
        s16x8 a1 = xb[64 + laneofs];
        s16x8 a2 = sh.hbuf[laneofs];
        s16x8 a3 = sh.hbuf[64 + laneofs];
#pragma unroll
        for (int i = 0; i < 4; ++i) {
            f32x4 d = {bv[i], bv[i], bv[i], bv[i]};
            d = __builtin_amdgcn_mfma_f32_16x16x32_bf16(a0, bf[i][0], d, 0, 0, 0);
            d = __builtin_amdgcn_mfma_f32_16x16x32_bf16(a1, bf[i][1], d, 0, 0, 0);
            d = __builtin_amdgcn_mfma_f32_16x16x32_bf16(a2, bf[i][2], d, 0, 0, 0);
            d = __builtin_amdgcn_mfma_f32_16x16x32_bf16(a3, bf[i][3], d, 0, 0, 0);
            if (i < cnt) {
                int g = colj[i];
#pragma unroll
                for (int r = 0; r < 4; ++r) sh.gbuf[srow + r][g] = d[r];
            }
        }
        __syncthreads();   // gbuf complete (and next-t x staged)

        // ---- update phase: c,h + fused masked pool ----
#define UPD(UU, CST, MR) { \
    int uu = (UU); \
    if (uu < 800) { \
        int s = uu / 50, c = uu - s * 50; \
        float gi = sh.gbuf[s][c]; \
        float gf = sh.gbuf[s][c + 50]; \
        float gg = sh.gbuf[s][c + 100]; \
        float go = sh.gbuf[s][c + 150]; \
        float cc = sigm(gf) * (CST) + sigm(gi) * tanh_fast(gg); \
        float h  = sigm(go) * tanh_fast(cc); \
        CST = cc; \
        ((unsigned short*)sh.hbuf)[((c >> 3) * 16 + s) * 8 + (c & 7)] = f2bf(h); \
        int tt = dir ? (sh.slen[s] - 1 - t) : t; \
        if (tt >= 0 && ((sh.smask[s] >> tt) & 1)) MR = fmaxf(MR, h); \
    } }
        UPD(tid,       cst0, mr0)
        UPD(tid + 256, cst1, mr1)
        UPD(tid + 512, cst2, mr2)
        UPD(tid + 768, cst3, mr3)
        __syncthreads();   // hbuf ready for next step
    }

    // ---- epilogue: pooled outputs ----
#define OUTW(UU, MR) { \
    int uu = (UU); \
    if (uu < 800) { \
        int s = uu / 50, c = uu - s * 50; \
        float m = (MR); \
        if (dir && (sh.smask[s] >> sh.slen[s])) m = fmaxf(m, 0.f); \
        if (m == NEGV) m = 0.f; \
        out[(size_t)(grp * 16 + s) * 968 + 868 + dir * CD_ + c] = m; \
    } }
    OUTW(tid,       mr0)
    OUTW(tid + 256, mr1)
    OUTW(tid + 512, mr2)
    OUTW(tid + 768, mr3)
}

// ================== Kernel 2: word_reps maxpool + word_embed + cls ==================
__global__ __launch_bounds__(256) void kword(const float* __restrict__ bert, const int* __restrict__ p2w,
                                             const int* __restrict__ word_ids, const float* __restrict__ word_table,
                                             float* __restrict__ out) {
    int bl = blockIdx.x;          // b*128 + l
    int b = bl >> 7;
    int l = bl & 127;
    int tid = threadIdx.x;

    __shared__ int list[S_ + 4];
    __shared__ int cnt;
    __shared__ float red[256];
    if (tid == 0) cnt = 0;
    __syncthreads();
    if (tid < S_) {
        if (p2w[bl * S_ + tid]) {
            int p = atomicAdd(&cnt, 1);   // order-independent: fmax is exact-commutative
            list[p] = tid;
        }
    }
    __syncthreads();
    int n = cnt;

    float a0, a1, a2;
    if (n > 0) {                          // n is block-uniform
        a0 = a1 = a2 = -FMAXV;
        if (tid < ((4 - (n & 3)) & 3)) list[n + tid] = list[0];   // pad (idempotent under fmax)
        __syncthreads();
        int n4 = (n + 3) & ~3;
        const float* bb = bert + (size_t)b * S_ * H_ + tid;
        for (int i = 0; i < n4; i += 4) {
            int s0 = list[i], s1 = list[i + 1], s2 = list[i + 2], s3 = list[i + 3];
            const float* r0 = bb + (size_t)s0 * H_;
            const float* r1 = bb + (size_t)s1 * H_;
            const float* r2 = bb + (size_t)s2 * H_;
            const float* r3 = bb + (size_t)s3 * H_;
            float v00 = r0[0],   v10 = r1[0],   v20 = r2[0],   v30 = r3[0];
            float v01 = r0[256], v11 = r1[256], v21 = r2[256], v31 = r3[256];
            float v02 = r0[512], v12 = r1[512], v22 = r2[512], v32 = r3[512];
            a0 = fmaxf(a0, fmaxf(fmaxf(v00, v10), fmaxf(v20, v30)));
            a1 = fmaxf(a1, fmaxf(fmaxf(v01, v11), fmaxf(v21, v31)));
            a2 = fmaxf(a2, fmaxf(fmaxf(v02, v12), fmaxf(v22, v32)));
        }
    } else {
        // all-masked word (probability ~2^-160; kept for strict correctness):
        // result = global min of bert_emb, computed locally.
        float m = FMAXV;
        const float4* x4 = (const float4*)bert;
        for (int i = tid; i < NELEM / 4; i += 256) {
            float4 v = x4[i];
            m = fminf(m, fminf(fminf(v.x, v.y), fminf(v.z, v.w)));
        }
        red[tid] = m;
        __syncthreads();
        for (int o = 128; o > 0; o >>= 1) {
            if (tid < o) red[tid] = fminf(red[tid], red[tid + o]);
            __syncthreads();
        }
        a0 = a1 = a2 = red[0];
    }

    float* orow = out + (size_t)bl * 968;
    orow[tid] = a0; orow[tid + 256] = a1; orow[tid + 512] = a2;

    if (tid < WD_) {
        int wid = word_ids[bl];
        orow[768 + tid] = word_table[(size_t)wid * WD_ + tid];
    }
    if (l == 0) {   // cls embedding = bert_emb[b,0,:]
        const float* c = bert + (size_t)b * S_ * H_;
        float* co = out + (size_t)B_ * L_ * 968 + (size_t)b * H_;
        co[tid] = c[tid]; co[tid + 256] = c[tid + 256]; co[tid + 512] = c[tid + 512];
    }
}

extern "C" void kernel_launch(void* const* d_in, const int* in_sizes, int n_in,
                              void* d_out, int out_size, void* d_ws, size_t ws_size,
                              hipStream_t stream) {
    const float* bert       = (const float*)d_in[0];
    const int*   p2w        = (const int*)d_in[1];
    const int*   word_ids   = (const int*)d_in[2];
    const int*   char_ids   = (const int*)d_in[3];
    const int*   char_count = (const int*)d_in[4];
    const int*   tok_mask   = (const int*)d_in[5];
    const float* word_table = (const float*)d_in[6];
    const float* char_table = (const float*)d_in[7];
    const float* w_ih_f = (const float*)d_in[8];
    const float* w_hh_f = (const float*)d_in[9];
    const float* b_f    = (const float*)d_in[10];
    const float* w_ih_b = (const float*)d_in[11];
    const float* w_hh_b = (const float*)d_in[12];
    const float* b_b    = (const float*)d_in[13];

    float* out = (float*)d_out;

    klstm_mfma<<<128, 256, 0, stream>>>(char_ids, char_count, tok_mask, char_table,
                                        w_ih_f, w_hh_f, b_f, w_ih_b, w_hh_b, b_b, out);
    kword<<<B_ * L_, 256, 0, stream>>>(bert, p2w, word_ids, word_table, out);
}

// Round 9
// 53.203 us; speedup vs baseline: 1.9165x; 1.1617x over previous
//
#include <hip/hip_runtime.h>

// Problem constants
#define B_   8
#define L_   128
#define S_   160
#define H_   768
#define T_   16
#define CD_  50
#define WD_  100
#define NGATE 200   // 4*CD
#define NEGV (-1e30f)
#define FMAXV 3.402823466e+38f
#define NELEM (B_ * S_ * H_)      // 983040 floats in bert_emb

typedef short  s16x8 __attribute__((ext_vector_type(8)));   // 8 bf16 in 4 VGPRs
typedef float  f32x4 __attribute__((ext_vector_type(4)));

__device__ __forceinline__ unsigned short f2bf(float f) {   // f32 -> bf16 RNE
    unsigned u = __float_as_uint(f);
    u = (u + 0x7FFFu + ((u >> 16) & 1u)) >> 16;
    return (unsigned short)u;
}
__device__ __forceinline__ float sigm(float x) {
    return __fdividef(1.f, 1.f + __expf(-x));
}
__device__ __forceinline__ float tanh_fast(float x) {
    float a = fabsf(x);
    float e = __expf(-2.f * a);
    float t = __fdividef(1.f - e, 1.f + e);
    return copysignf(t, x);
}

// ================== Kernel 1: MFMA BiLSTM (16 seqs/block, 128 blocks) ==================
// K-concat: k 0..63 = x (50 real), k 64..127 = h (50 real). 4 K-tiles of 32.
// A-frag LDS unit (kt*4+kg)*16 + s holds 8 bf16 (k = kt*32+kg*8+e) of seq s.
// ALL 16 timesteps of x prestaged -> t-loop has ZERO global memory ops.
struct LstmS {
    s16x8 xall[T_][128];  // x A-frags for every t                 32768 B
    s16x8 hbuf[128];      // h A-frags (K-tiles 2,3)                2048 B
    float gbuf[16][212];  // gates f32 [seq][gate], padded stride  13568 B
    int   slen[16], smask[16];
};

__global__ __launch_bounds__(256, 1) void klstm_mfma(
        const int* __restrict__ char_ids, const int* __restrict__ char_count,
        const int* __restrict__ tok_mask, const float* __restrict__ char_table,
        const float* __restrict__ w_ih_f, const float* __restrict__ w_hh_f,
        const float* __restrict__ b_f,
        const float* __restrict__ w_ih_b, const float* __restrict__ w_hh_b,
        const float* __restrict__ b_b,
        float* __restrict__ out) {
    __shared__ LstmS sh;
    const int unit = blockIdx.x;       // 0..127
    const int dir  = unit >> 6;
    const int grp  = unit & 63;        // 16 seqs: grp*16 ..
    const int tid  = threadIdx.x;
    const int lane = tid & 63;
    const int wv   = tid >> 6;

    // ---- prologue: metadata ----
    if (tid < 16) {
        int n = grp * 16 + tid;
        int c = char_count[n];
        sh.slen[tid] = (c > 0) ? c : 1;
        int mb = 0;
        for (int t = 0; t < T_; ++t) mb |= (tok_mask[n * T_ + t] != 0) << t;
        sh.smask[tid] = mb;
    }
    if (tid < 128) { s16x8 z = {0,0,0,0,0,0,0,0}; sh.hbuf[tid] = z; }

    // ---- B-fragments (weights) -> registers, once. wave wv owns N-tiles {wv, wv+4, wv+8 (,12)} ----
    const float* WI = dir ? w_ih_b : w_ih_f;
    const float* WH = dir ? w_hh_b : w_hh_f;
    const float* BV = dir ? b_b    : b_f;
    const int cnt = (wv == 0) ? 4 : 3;
    int   colj[4];
    float bv[4];
    s16x8 bf[4][4];
#pragma unroll
    for (int i = 0; i < 4; ++i) {
        int nt = (i < 3) ? (wv + 4 * i) : 12;
        int j  = nt * 16 + (lane & 15);
        bool jv = (i < cnt) && (j < NGATE);
        colj[i] = j;
        bv[i]   = jv ? BV[j] : 0.f;
        const float* wi = WI + j * CD_;
        const float* wh = WH + j * CD_;
#pragma unroll
        for (int kt = 0; kt < 4; ++kt) {
            int kst = kt * 32 + (lane >> 4) * 8;
            s16x8 fr = {0,0,0,0,0,0,0,0};
#pragma unroll
            for (int e = 0; e < 8; ++e) {
                int k = kst + e;
                float v = 0.f;
                if (jv) {
                    if (k < 64) { if (k < CD_) v = wi[k]; }
                    else        { int k2 = k - 64; if (k2 < CD_) v = wh[k2]; }
                }
                fr[e] = (short)f2bf(v);
            }
            bf[i][kt] = fr;
        }
    }
    __syncthreads();   // slen ready

    // ---- prestage ALL x A-frags (16 t x 128 units); reversed+zero-pad for bwd ----
    for (int idx = tid; idx < T_ * 128; idx += 256) {
        int t = idx >> 7;
        int u = idx & 127;
        int g = u >> 4, s = u & 15;
        int st = dir ? (sh.slen[s] - 1 - t) : t;
        s16x8 fr = {0,0,0,0,0,0,0,0};
        if (st >= 0) {
            int cidv = char_ids[(grp * 16 + s) * T_ + st];
            const float* row = char_table + cidv * CD_;
            int kbase = g * 8;
#pragma unroll
            for (int e = 0; e < 8; ++e) {
                int k = kbase + e;
                if (k < CD_) fr[e] = (short)f2bf(row[k]);
            }
        }
        sh.xall[t][u] = fr;
    }

    const int laneofs = ((lane >> 4) << 4) + (lane & 15);   // kg*16 + s
    const int srow    = (lane >> 4) * 4;                    // D rows 4*(l>>4)+r

    // ---- update-phase slots: thread owns units tid, +256, +512, +768 (<800); hoist invariants ----
#define SLOT_DECL(K, UU) \
    const int  uu##K = (UU); \
    const bool v##K  = uu##K < 800; \
    const int  s##K  = v##K ? (uu##K / 50) : 0; \
    const int  c##K  = uu##K - s##K * 50; \
    const int  hofs##K = ((c##K >> 3) * 16 + s##K) * 8 + (c##K & 7); \
    int  sl##K = 1, sm##K = 0; \
    float cst##K = 0.f, mr##K = NEGV;
    SLOT_DECL(0, tid)
    SLOT_DECL(1, tid + 256)
    SLOT_DECL(2, tid + 512)
    SLOT_DECL(3, tid + 768)
    sl0 = sh.slen[s0]; sm0 = sh.smask[s0];
    sl1 = sh.slen[s1]; sm1 = sh.smask[s1];
    sl2 = sh.slen[s2]; sm2 = sh.smask[s2];
    sl3 = sh.slen[s3]; sm3 = sh.smask[s3];
    __syncthreads();   // xall + hbuf ready

#pragma unroll 1
    for (int t = 0; t < T_; ++t) {
        // ---- MFMA phase: gates = [x|h] * W'^T + bias ----
        const s16x8* xb = sh.xall[t];
        s16x8 a0 = xb[laneofs];
        s16x8 a1 = xb[64 + laneofs];
        s16x8 a2 = sh.hbuf[laneofs];
        s16x8 a3 = sh.hbuf[64 + laneofs];
#pragma unroll
        for (int i = 0; i < 4; ++i) {
            f32x4 d = {bv[i], bv[i], bv[i], bv[i]};
            d = __builtin_amdgcn_mfma_f32_16x16x32_bf16(a0, bf[i][0], d, 0, 0, 0);
            d = __builtin_amdgcn_mfma_f32_16x16x32_bf16(a1, bf[i][1], d, 0, 0, 0);
            d = __builtin_amdgcn_mfma_f32_16x16x32_bf16(a2, bf[i][2], d, 0, 0, 0);
            d = __builtin_amdgcn_mfma_f32_16x16x32_bf16(a3, bf[i][3], d, 0, 0, 0);
            if (i < cnt) {
                int g = colj[i];
#pragma unroll
                for (int r = 0; r < 4; ++r) sh.gbuf[srow + r][g] = d[r];
            }
        }
        __syncthreads();   // gbuf complete

        // ---- update phase: c,h + fused masked pool (all addresses precomputed) ----
#define UPD(K) if (v##K) { \
    float gi = sh.gbuf[s##K][c##K]; \
    float gf = sh.gbuf[s##K][c##K + 50]; \
    float gg = sh.gbuf[s##K][c##K + 100]; \
    float go = sh.gbuf[s##K][c##K + 150]; \
    float cc = sigm(gf) * cst##K + sigm(gi) * tanh_fast(gg); \
    float h  = sigm(go) * tanh_fast(cc); \
    cst##K = cc; \
    ((unsigned short*)sh.hbuf)[hofs##K] = f2bf(h); \
    int tt = dir ? (sl##K - 1 - t) : t; \
    if (tt >= 0 && ((sm##K >> tt) & 1)) mr##K = fmaxf(mr##K, h); }
        UPD(0) UPD(1) UPD(2) UPD(3)
        __syncthreads();   // hbuf ready for next step
    }

    // ---- epilogue: pooled outputs ----
#define OUTW(K) if (v##K) { \
    float m = mr##K; \
    if (dir && (sm##K >> sl##K)) m = fmaxf(m, 0.f); \
    if (m == NEGV) m = 0.f; \
    out[(size_t)(grp * 16 + s##K) * 968 + 868 + dir * CD_ + c##K] = m; }
    OUTW(0) OUTW(1) OUTW(2) OUTW(3)
}

// ================== Kernel 2: word_reps maxpool (float4) + word_embed + cls ==================
__device__ __forceinline__ float4 fmax4(float4 a, float4 b) {
    return make_float4(fmaxf(a.x, b.x), fmaxf(a.y, b.y), fmaxf(a.z, b.z), fmaxf(a.w, b.w));
}

__global__ __launch_bounds__(256) void kword(const float* __restrict__ bert, const int* __restrict__ p2w,
                                             const int* __restrict__ word_ids, const float* __restrict__ word_table,
                                             float* __restrict__ out) {
    int bl = blockIdx.x;          // b*128 + l
    int b = bl >> 7;
    int l = bl & 127;
    int tid = threadIdx.x;

    __shared__ int list[S_ + 4];
    __shared__ int cnt;
    __shared__ float red[256];
    if (tid == 0) cnt = 0;
    __syncthreads();
    if (tid < S_) {
        if (p2w[bl * S_ + tid]) {
            int p = atomicAdd(&cnt, 1);   // order-independent: fmax is exact-commutative
            list[p] = tid;
        }
    }
    __syncthreads();
    int n = cnt;

    float* orow = out + (size_t)bl * 968;

    if (n > 0) {                          // n is block-uniform
        if (tid < ((4 - (n & 3)) & 3)) list[n + tid] = list[0];   // pad (idempotent under fmax)
        __syncthreads();
        int n4 = (n + 3) & ~3;
        if (tid < 192) {
            // threads 0..191: pool H=768 as 192 float4 columns (fully coalesced 16B/lane)
            const float4* bb = (const float4*)(bert + (size_t)b * S_ * H_) + tid;
            float4 m = make_float4(-FMAXV, -FMAXV, -FMAXV, -FMAXV);
            for (int i = 0; i < n4; i += 4) {
                int s0 = list[i], s1 = list[i + 1], s2 = list[i + 2], s3 = list[i + 3];
                float4 v0 = bb[(size_t)s0 * 192];
                float4 v1 = bb[(size_t)s1 * 192];
                float4 v2 = bb[(size_t)s2 * 192];
                float4 v3 = bb[(size_t)s3 * 192];
                m = fmax4(m, fmax4(fmax4(v0, v1), fmax4(v2, v3)));
            }
            ((float4*)orow)[tid] = m;
        } else {
            // threads 192..255: word_embed gather (runs concurrently with the pool loop)
            int j = tid - 192;
            int wid = word_ids[bl];
            orow[768 + j] = word_table[(size_t)wid * WD_ + j];
            if (j < WD_ - 64) orow[768 + 64 + j] = word_table[(size_t)wid * WD_ + 64 + j];
        }
    } else {
        // all-masked word (probability ~2^-160; kept for strict correctness):
        // result = global min of bert_emb, computed locally.
        float mv = FMAXV;
        const float4* x4 = (const float4*)bert;
        for (int i = tid; i < NELEM / 4; i += 256) {
            float4 v = x4[i];
            mv = fminf(mv, fminf(fminf(v.x, v.y), fminf(v.z, v.w)));
        }
        red[tid] = mv;
        __syncthreads();
        for (int o = 128; o > 0; o >>= 1) {
            if (tid < o) red[tid] = fminf(red[tid], red[tid + o]);
            __syncthreads();
        }
        float g = red[0];
        if (tid < 192) {
            ((float4*)orow)[tid] = make_float4(g, g, g, g);
        } else {
            int j = tid - 192;
            int wid = word_ids[bl];
            orow[768 + j] = word_table[(size_t)wid * WD_ + j];
            if (j < WD_ - 64) orow[768 + 64 + j] = word_table[(size_t)wid * WD_ + 64 + j];
        }
    }

    if (l == 0 && tid < 192) {   // cls embedding = bert_emb[b,0,:]
        const float4* c4 = (const float4*)(bert + (size_t)b * S_ * H_);
        float4* co = (float4*)(out + (size_t)B_ * L_ * 968 + (size_t)b * H_);
        co[tid] = c4[tid];
    }
}

extern "C" void kernel_launch(void* const* d_in, const int* in_sizes, int n_in,
                              void* d_out, int out_size, void* d_ws, size_t ws_size,
                              hipStream_t stream) {
    const float* bert       = (const float*)d_in[0];
    const int*   p2w        = (const int*)d_in[1];
    const int*   word_ids   = (const int*)d_in[2];
    const int*   char_ids   = (const int*)d_in[3];
    const int*   char_count = (const int*)d_in[4];
    const int*   tok_mask   = (const int*)d_in[5];
    const float* word_table = (const float*)d_in[6];
    const float* char_table = (const float*)d_in[7];
    const float* w_ih_f = (const float*)d_in[8];
    const float* w_hh_f = (const float*)d_in[9];
    const float* b_f    = (const float*)d_in[10];
    const float* w_ih_b = (const float*)d_in[11];
    const float* w_hh_b = (const float*)d_in[12];
    const float* b_b    = (const float*)d_in[13];

    float* out = (float*)d_out;

    klstm_mfma<<<128, 256, 0, stream>>>(char_ids, char_count, tok_mask, char_table,
                                        w_ih_f, w_hh_f, b_f, w_ih_b, w_hh_b, b_b, out);
    kword<<<B_ * L_, 256, 0, stream>>>(bert, p2w, word_ids, word_table, out);
}

// Round 10
// 44.973 us; speedup vs baseline: 2.2673x; 1.1830x over previous
//
#include <hip/hip_runtime.h>

// Problem constants
#define B_   8
#define L_   128
#define S_   160
#define H_   768
#define T_   16
#define CD_  50
#define WD_  100
#define NGATE 200   // 4*CD
#define NEGV (-1e30f)
#define FMAXV 3.402823466e+38f
#define NELEM (B_ * S_ * H_)      // 983040 floats in bert_emb

typedef short  s16x8 __attribute__((ext_vector_type(8)));   // 8 bf16 in 4 VGPRs
typedef float  f32x4 __attribute__((ext_vector_type(4)));

__device__ __forceinline__ unsigned short f2bf(float f) {   // f32 -> bf16 RNE
    unsigned u = __float_as_uint(f);
    u = (u + 0x7FFFu + ((u >> 16) & 1u)) >> 16;
    return (unsigned short)u;
}
__device__ __forceinline__ float sigm(float x) {
    return __fdividef(1.f, 1.f + __expf(-x));
}
__device__ __forceinline__ float tanh_fast(float x) {
    float a = fabsf(x);
    float e = __expf(-2.f * a);
    float t = __fdividef(1.f - e, 1.f + e);
    return copysignf(t, x);
}
__device__ __forceinline__ float4 fmax4(float4 a, float4 b) {
    return make_float4(fmaxf(a.x, b.x), fmaxf(a.y, b.y), fmaxf(a.z, b.z), fmaxf(a.w, b.w));
}

#define GSTRIDE 213   // odd -> gcd(213%32,32)=1, no systematic LDS bank aliasing

// ---------------- shared-memory overlays ----------------
struct LstmS {
    s16x8 xall[T_][128];      // x A-frags for every t              32768 B
    s16x8 hbuf[128];          // h A-frags (K-tiles 2,3)             2048 B
    float gbuf[16][GSTRIDE];  // gates f32 [seq][gate]              13632 B
    int   slen[16], smask[16];
};
struct WordS {
    int list[S_ + 4];
    int cnt;
    float red[256];
};
#define SMEM_BYTES 48704      // >= sizeof(LstmS) ~48576, 16B aligned

// ================== role A: MFMA BiLSTM (16 seqs/unit, units 0..127) ==================
// K-concat: k 0..63 = x (50 real), k 64..127 = h (50 real). 4 K-tiles of 32.
// A-frag LDS unit (kt*4+kg)*16 + s holds 8 bf16 (k = kt*32+kg*8+e) of seq s.
// ALL 16 timesteps of x prestaged -> t-loop has ZERO global memory ops.
__device__ void lstm_body(int unit, char* smem,
        const int* __restrict__ char_ids, const int* __restrict__ char_count,
        const int* __restrict__ tok_mask, const float* __restrict__ char_table,
        const float* __restrict__ w_ih_f, const float* __restrict__ w_hh_f,
        const float* __restrict__ b_f,
        const float* __restrict__ w_ih_b, const float* __restrict__ w_hh_b,
        const float* __restrict__ b_b,
        float* __restrict__ out) {
    LstmS& sh = *(LstmS*)smem;
    const int dir  = unit >> 6;
    const int grp  = unit & 63;        // 16 seqs: grp*16 ..
    const int tid  = threadIdx.x;
    const int lane = tid & 63;
    const int wv   = tid >> 6;

    // ---- prologue: metadata ----
    if (tid < 16) {
        int n = grp * 16 + tid;
        int c = char_count[n];
        sh.slen[tid] = (c > 0) ? c : 1;
        int mb = 0;
        for (int t = 0; t < T_; ++t) mb |= (tok_mask[n * T_ + t] != 0) << t;
        sh.smask[tid] = mb;
    }
    if (tid < 128) { s16x8 z = {0,0,0,0,0,0,0,0}; sh.hbuf[tid] = z; }

    // ---- B-fragments (weights) -> registers, once. wave wv owns N-tiles {wv, wv+4, wv+8 (,12)} ----
    const float* WI = dir ? w_ih_b : w_ih_f;
    const float* WH = dir ? w_hh_b : w_hh_f;
    const float* BV = dir ? b_b    : b_f;
    const int cnt = (wv == 0) ? 4 : 3;
    int   colj[4];
    float bv[4];
    s16x8 bf[4][4];
#pragma unroll
    for (int i = 0; i < 4; ++i) {
        int nt = (i < 3) ? (wv + 4 * i) : 12;
        int j  = nt * 16 + (lane & 15);
        bool jv = (i < cnt) && (j < NGATE);
        colj[i] = j;
        bv[i]   = jv ? BV[j] : 0.f;
        const float* wi = WI + j * CD_;
        const float* wh = WH + j * CD_;
#pragma unroll
        for (int kt = 0; kt < 4; ++kt) {
            int kst = kt * 32 + (lane >> 4) * 8;
            s16x8 fr = {0,0,0,0,0,0,0,0};
#pragma unroll
            for (int e = 0; e < 8; ++e) {
                int k = kst + e;
                float v = 0.f;
                if (jv) {
                    if (k < 64) { if (k < CD_) v = wi[k]; }
                    else        { int k2 = k - 64; if (k2 < CD_) v = wh[k2]; }
                }
                fr[e] = (short)f2bf(v);
            }
            bf[i][kt] = fr;
        }
    }
    __syncthreads();   // slen ready

    // ---- prestage ALL x A-frags (16 t x 128 units); reversed+zero-pad for bwd ----
    for (int idx = tid; idx < T_ * 128; idx += 256) {
        int t = idx >> 7;
        int u = idx & 127;
        int g = u >> 4, s = u & 15;
        int st = dir ? (sh.slen[s] - 1 - t) : t;
        s16x8 fr = {0,0,0,0,0,0,0,0};
        if (st >= 0) {
            int cidv = char_ids[(grp * 16 + s) * T_ + st];
            const float* row = char_table + cidv * CD_;
            int kbase = g * 8;
#pragma unroll
            for (int e = 0; e < 8; ++e) {
                int k = kbase + e;
                if (k < CD_) fr[e] = (short)f2bf(row[k]);
            }
        }
        sh.xall[t][u] = fr;
    }

    const int laneofs = ((lane >> 4) << 4) + (lane & 15);   // kg*16 + s
    const int srow    = (lane >> 4) * 4;                    // D rows 4*(l>>4)+r

    // ---- update-phase slots: thread owns units tid, +256, +512, +768 (<800); hoisted ----
#define SLOT_DECL(K, UU) \
    const int  uu##K = (UU); \
    const bool v##K  = uu##K < 800; \
    const int  s##K  = v##K ? (uu##K / 50) : 0; \
    const int  c##K  = uu##K - s##K * 50; \
    const int  hofs##K = ((c##K >> 3) * 16 + s##K) * 8 + (c##K & 7); \
    int  sl##K = 1, sm##K = 0; \
    float cst##K = 0.f, mr##K = NEGV;
    SLOT_DECL(0, tid)
    SLOT_DECL(1, tid + 256)
    SLOT_DECL(2, tid + 512)
    SLOT_DECL(3, tid + 768)
    sl0 = sh.slen[s0]; sm0 = sh.smask[s0];
    sl1 = sh.slen[s1]; sm1 = sh.smask[s1];
    sl2 = sh.slen[s2]; sm2 = sh.smask[s2];
    sl3 = sh.slen[s3]; sm3 = sh.smask[s3];
    __syncthreads();   // xall + hbuf ready

#pragma unroll 1
    for (int t = 0; t < T_; ++t) {
        // ---- MFMA phase: gates = [x|h] * W'^T + bias ----
        const s16x8* xb = sh.xall[t];
        s16x8 a0 = xb[laneofs];
        s16x8 a1 = xb[64 + laneofs];
        s16x8 a2 = sh.hbuf[laneofs];
        s16x8 a3 = sh.hbuf[64 + laneofs];
#pragma unroll
        for (int i = 0; i < 4; ++i) {
            f32x4 d = {bv[i], bv[i], bv[i], bv[i]};
            d = __builtin_amdgcn_mfma_f32_16x16x32_bf16(a0, bf[i][0], d, 0, 0, 0);
            d = __builtin_amdgcn_mfma_f32_16x16x32_bf16(a1, bf[i][1], d, 0, 0, 0);
            d = __builtin_amdgcn_mfma_f32_16x16x32_bf16(a2, bf[i][2], d, 0, 0, 0);
            d = __builtin_amdgcn_mfma_f32_16x16x32_bf16(a3, bf[i][3], d, 0, 0, 0);
            if (i < cnt) {
                int g = colj[i];
#pragma unroll
                for (int r = 0; r < 4; ++r) sh.gbuf[srow + r][g] = d[r];
            }
        }
        __syncthreads();   // gbuf complete

        // ---- update phase: c,h + fused masked pool (addresses precomputed) ----
#define UPD(K) if (v##K) { \
    float gi = sh.gbuf[s##K][c##K]; \
    float gf = sh.gbuf[s##K][c##K + 50]; \
    float gg = sh.gbuf[s##K][c##K + 100]; \
    float go = sh.gbuf[s##K][c##K + 150]; \
    float cc = sigm(gf) * cst##K + sigm(gi) * tanh_fast(gg); \
    float h  = sigm(go) * tanh_fast(cc); \
    cst##K = cc; \
    ((unsigned short*)sh.hbuf)[hofs##K] = f2bf(h); \
    int tt = dir ? (sl##K - 1 - t) : t; \
    if (tt >= 0 && ((sm##K >> tt) & 1)) mr##K = fmaxf(mr##K, h); }
        UPD(0) UPD(1) UPD(2) UPD(3)
        __syncthreads();   // hbuf ready for next step
    }

    // ---- epilogue: pooled outputs ----
#define OUTW(K) if (v##K) { \
    float m = mr##K; \
    if (dir && (sm##K >> sl##K)) m = fmaxf(m, 0.f); \
    if (m == NEGV) m = 0.f; \
    out[(size_t)(grp * 16 + s##K) * 968 + 868 + dir * CD_ + c##K] = m; }
    OUTW(0) OUTW(1) OUTW(2) OUTW(3)
}

// ================== role B: word_reps maxpool (float4) + word_embed + cls ==================
__device__ void word_body(int bl, char* smem,
        const float* __restrict__ bert, const int* __restrict__ p2w,
        const int* __restrict__ word_ids, const float* __restrict__ word_table,
        float* __restrict__ out) {
    WordS& sh = *(WordS*)smem;
    int b = bl >> 7;
    int l = bl & 127;
    int tid = threadIdx.x;

    if (tid == 0) sh.cnt = 0;
    __syncthreads();
    if (tid < S_) {
        if (p2w[bl * S_ + tid]) {
            int p = atomicAdd(&sh.cnt, 1);   // order-independent: fmax is exact-commutative
            sh.list[p] = tid;
        }
    }
    __syncthreads();
    int n = sh.cnt;

    float* orow = out + (size_t)bl * 968;

    if (n > 0) {                          // n is block-uniform
        if (tid < ((4 - (n & 3)) & 3)) sh.list[n + tid] = sh.list[0];   // pad (idempotent)
        __syncthreads();
        int n4 = (n + 3) & ~3;
        if (tid < 192) {
            // threads 0..191: pool H=768 as 192 float4 columns (coalesced 16B/lane)
            const float4* bb = (const float4*)(bert + (size_t)b * S_ * H_) + tid;
            float4 m = make_float4(-FMAXV, -FMAXV, -FMAXV, -FMAXV);
            for (int i = 0; i < n4; i += 4) {
                int s0 = sh.list[i], s1 = sh.list[i + 1], s2 = sh.list[i + 2], s3 = sh.list[i + 3];
                float4 v0 = bb[(size_t)s0 * 192];
                float4 v1 = bb[(size_t)s1 * 192];
                float4 v2 = bb[(size_t)s2 * 192];
                float4 v3 = bb[(size_t)s3 * 192];
                m = fmax4(m, fmax4(fmax4(v0, v1), fmax4(v2, v3)));
            }
            ((float4*)orow)[tid] = m;
        } else {
            // threads 192..255: word_embed gather (concurrent with the pool loop)
            int j = tid - 192;
            int wid = word_ids[bl];
            orow[768 + j] = word_table[(size_t)wid * WD_ + j];
            if (j < WD_ - 64) orow[768 + 64 + j] = word_table[(size_t)wid * WD_ + 64 + j];
        }
    } else {
        // all-masked word (probability ~2^-160; kept for strict correctness)
        float mv = FMAXV;
        const float4* x4 = (const float4*)bert;
        for (int i = tid; i < NELEM / 4; i += 256) {
            float4 v = x4[i];
            mv = fminf(mv, fminf(fminf(v.x, v.y), fminf(v.z, v.w)));
        }
        sh.red[tid] = mv;
        __syncthreads();
        for (int o = 128; o > 0; o >>= 1) {
            if (tid < o) sh.red[tid] = fminf(sh.red[tid], sh.red[tid + o]);
            __syncthreads();
        }
        float g = sh.red[0];
        if (tid < 192) {
            ((float4*)orow)[tid] = make_float4(g, g, g, g);
        } else {
            int j = tid - 192;
            int wid = word_ids[bl];
            orow[768 + j] = word_table[(size_t)wid * WD_ + j];
            if (j < WD_ - 64) orow[768 + 64 + j] = word_table[(size_t)wid * WD_ + 64 + j];
        }
    }

    if (l == 0 && tid < 192) {   // cls embedding = bert_emb[b,0,:]
        const float4* c4 = (const float4*)(bert + (size_t)b * S_ * H_);
        float4* co = (float4*)(out + (size_t)B_ * L_ * 968 + (size_t)b * H_);
        co[tid] = c4[tid];
    }
}

// ================== mega kernel: 128 LSTM blocks first, 1024 word blocks backfill ==================
__global__ __launch_bounds__(256, 3) void kmega(
        const float* __restrict__ bert, const int* __restrict__ p2w,
        const int* __restrict__ word_ids, const int* __restrict__ char_ids,
        const int* __restrict__ char_count, const int* __restrict__ tok_mask,
        const float* __restrict__ word_table, const float* __restrict__ char_table,
        const float* __restrict__ w_ih_f, const float* __restrict__ w_hh_f,
        const float* __restrict__ b_f,
        const float* __restrict__ w_ih_b, const float* __restrict__ w_hh_b,
        const float* __restrict__ b_b,
        float* __restrict__ out) {
    __shared__ __align__(16) char smem[SMEM_BYTES];
    int bid = blockIdx.x;
    if (bid < 128) {
        lstm_body(bid, smem, char_ids, char_count, tok_mask, char_table,
                  w_ih_f, w_hh_f, b_f, w_ih_b, w_hh_b, b_b, out);
    } else {
        word_body(bid - 128, smem, bert, p2w, word_ids, word_table, out);
    }
}

extern "C" void kernel_launch(void* const* d_in, const int* in_sizes, int n_in,
                              void* d_out, int out_size, void* d_ws, size_t ws_size,
                              hipStream_t stream) {
    const float* bert       = (const float*)d_in[0];
    const int*   p2w        = (const int*)d_in[1];
    const int*   word_ids   = (const int*)d_in[2];
    const int*   char_ids   = (const int*)d_in[3];
    const int*   char_count = (const int*)d_in[4];
    const int*   tok_mask   = (const int*)d_in[5];
    const float* word_table = (const float*)d_in[6];
    const float* char_table = (const float*)d_in[7];
    const float* w_ih_f = (const float*)d_in[8];
    const float* w_hh_f = (const float*)d_in[9];
    const float* b_f    = (const float*)d_in[10];
    const float* w_ih_b = (const float*)d_in[11];
    const float* w_hh_b = (const float*)d_in[12];
    const float* b_b    = (const float*)d_in[13];

    float* out = (float*)d_out;

    kmega<<<128 + B_ * L_, 256, 0, stream>>>(bert, p2w, word_ids, char_ids, char_count, tok_mask,
                                             word_table, char_table,
                                             w_ih_f, w_hh_f, b_f, w_ih_b, w_hh_b, b_b, out);
}

// Round 11
// 44.948 us; speedup vs baseline: 2.2685x; 1.0006x over previous
//
#include <hip/hip_runtime.h>

// Problem constants
#define B_   8
#define L_   128
#define S_   160
#define H_   768
#define T_   16
#define CD_  50
#define WD_  100
#define NGATE 200   // 4*CD
#define NEGV (-1e30f)
#define FMAXV 3.402823466e+38f
#define NELEM (B_ * S_ * H_)      // 983040 floats in bert_emb

typedef short  s16x8 __attribute__((ext_vector_type(8)));   // 8 bf16 in 4 VGPRs
typedef float  f32x4 __attribute__((ext_vector_type(4)));

__device__ __forceinline__ unsigned short f2bf(float f) {   // f32 -> bf16 RNE
    unsigned u = __float_as_uint(f);
    u = (u + 0x7FFFu + ((u >> 16) & 1u)) >> 16;
    return (unsigned short)u;
}
__device__ __forceinline__ float sigm(float x) {
    return __fdividef(1.f, 1.f + __expf(-x));
}
__device__ __forceinline__ float tanh_fast(float x) {
    float a = fabsf(x);
    float e = __expf(-2.f * a);
    float t = __fdividef(1.f - e, 1.f + e);
    return copysignf(t, x);
}
__device__ __forceinline__ float4 fmax4(float4 a, float4 b) {
    return make_float4(fmaxf(a.x, b.x), fmaxf(a.y, b.y), fmaxf(a.z, b.z), fmaxf(a.w, b.w));
}

// ---------------- shared-memory overlays ----------------
struct LstmS {
    s16x8 xall[T_][128];   // x A-frags for every t              32768 B
    s16x8 hbuf[2][128];    // h A-frags, double-buffered          4096 B
    int   slen[16], smask[16];
};
struct WordS {
    int list[S_ + 8];
    int cnt;
    float red[256];
};
#define SMEM_BYTES 37120

// ================== role A: MFMA BiLSTM, gate-permuted weights ==================
// Weight N-order permuted: col j' = 4*cell + gatetype  (orig row = gatetype*50 + cell).
// After MFMA, the 4 gates of cell c sit in 4 ADJACENT lanes -> 2-stage shfl_xor 4x4
// transpose gives each lane all 4 gates of one (cell,seq): update fully in-register,
// no gate LDS buffer, ONE barrier per step (h double-buffered).
__device__ void lstm_body(int unit, char* smem,
        const int* __restrict__ char_ids, const int* __restrict__ char_count,
        const int* __restrict__ tok_mask, const float* __restrict__ char_table,
        const float* __restrict__ w_ih_f, const float* __restrict__ w_hh_f,
        const float* __restrict__ b_f,
        const float* __restrict__ w_ih_b, const float* __restrict__ w_hh_b,
        const float* __restrict__ b_b,
        float* __restrict__ out) {
    LstmS& sh = *(LstmS*)smem;
    const int dir  = unit >> 6;
    const int grp  = unit & 63;        // 16 seqs: grp*16 ..
    const int tid  = threadIdx.x;
    const int lane = tid & 63;
    const int wv   = tid >> 6;

    // ---- prologue: metadata + zero h buffers ----
    if (tid < 16) {
        int n = grp * 16 + tid;
        int c = char_count[n];
        sh.slen[tid] = (c > 0) ? c : 1;
        int mb = 0;
        for (int t = 0; t < T_; ++t) mb |= (tok_mask[n * T_ + t] != 0) << t;
        sh.smask[tid] = mb;
    }
    { s16x8 z = {0,0,0,0,0,0,0,0};
      if (tid < 128) sh.hbuf[0][tid] = z; else sh.hbuf[1][tid - 128] = z; }

    // ---- per-lane geometry ----
    const int m   = lane & 3;          // gate type (for B cols) / seq sub-idx (after transpose)
    const int k2  = (lane >> 2) & 3;   // cell sub-idx within tile
    const int q   = lane >> 4;
    const int sstar = q * 4 + m;       // seq owned after transpose (same for all tiles)

    // ---- B-fragments (permuted weights) -> registers, once ----
    const float* WI = dir ? w_ih_b : w_ih_f;
    const float* WH = dir ? w_hh_b : w_hh_f;
    const float* BV = dir ? b_b    : b_f;
    const int cnt = (wv == 0) ? 4 : 3;
    int   ccol[4];      // cell index per tile
    int   cvld[4];      // col valid per tile
    int   hofs[4];      // h writeback ushort offset per tile
    float bv[4];
    s16x8 bf[4][4];
#pragma unroll
    for (int i = 0; i < 4; ++i) {
        int nt = (i < 3) ? (wv + 4 * i) : 12;
        int c  = nt * 4 + k2;
        int jv = (i < cnt) && (c < 50);
        ccol[i] = c;
        cvld[i] = jv;
        hofs[i] = ((c >> 3) * 16 + sstar) * 8 + (c & 7);
        int orow = m * 50 + c;                      // original weight row (gate m, cell c)
        bv[i] = jv ? BV[orow] : 0.f;
        const float* wi = WI + orow * CD_;
        const float* wh = WH + orow * CD_;
#pragma unroll
        for (int kt = 0; kt < 4; ++kt) {
            int kst = kt * 32 + q * 8;
            s16x8 fr = {0,0,0,0,0,0,0,0};
#pragma unroll
            for (int e = 0; e < 8; ++e) {
                int k = kst + e;
                float v = 0.f;
                if (jv) {
                    if (k < 64) { if (k < CD_) v = wi[k]; }
                    else        { int kk = k - 64; if (kk < CD_) v = wh[kk]; }
                }
                fr[e] = (short)f2bf(v);
            }
            bf[i][kt] = fr;
        }
    }
    __syncthreads();   // slen ready

    // ---- prestage ALL x A-frags (16 t x 128 units); reversed+zero-pad for bwd ----
    for (int idx = tid; idx < T_ * 128; idx += 256) {
        int t = idx >> 7;
        int u = idx & 127;
        int g = u >> 4, s = u & 15;
        int st = dir ? (sh.slen[s] - 1 - t) : t;
        s16x8 fr = {0,0,0,0,0,0,0,0};
        if (st >= 0) {
            int cidv = char_ids[(grp * 16 + s) * T_ + st];
            const float* row = char_table + cidv * CD_;
            int kbase = g * 8;
#pragma unroll
            for (int e = 0; e < 8; ++e) {
                int k = kbase + e;
                if (k < CD_) fr[e] = (short)f2bf(row[k]);
            }
        }
        sh.xall[t][u] = fr;
    }

    const int laneofs = (q << 4) + (lane & 15);   // kg*16 + s16 (A-frag read offset)
    const int sl_s = sh.slen[sstar];   // note: slen written before first barrier
    const int sm_s = sh.smask[sstar];

    float cst0 = 0.f, cst1 = 0.f, cst2 = 0.f, cst3 = 0.f;
    float mr0 = NEGV, mr1 = NEGV, mr2 = NEGV, mr3 = NEGV;
    const bool m0 = (lane & 1) != 0;
    const bool m1 = (lane & 2) != 0;

    __syncthreads();   // xall + hbuf ready

    // transpose + in-register update for one tile
#define TRUPD(I, D) { \
    float v0 = (D)[0], v1 = (D)[1], v2 = (D)[2], v3 = (D)[3]; \
    float s10 = __shfl_xor(v0, 1), s11 = __shfl_xor(v1, 1); \
    float s12 = __shfl_xor(v2, 1), s13 = __shfl_xor(v3, 1); \
    float A0 = m0 ? s11 : v0; \
    float A1 = m0 ? v1 : s10; \
    float A2 = m0 ? s13 : v2; \
    float A3 = m0 ? v3 : s12; \
    float s20 = __shfl_xor(A0, 2), s21 = __shfl_xor(A1, 2); \
    float s22 = __shfl_xor(A2, 2), s23 = __shfl_xor(A3, 2); \
    float gi = m1 ? s22 : A0; \
    float gf = m1 ? s23 : A1; \
    float gg = m1 ? A2 : s20; \
    float go = m1 ? A3 : s21; \
    float cc = sigm(gf) * cst##I + sigm(gi) * tanh_fast(gg); \
    float h  = sigm(go) * tanh_fast(cc); \
    if (cvld[I]) { \
        cst##I = cc; \
        hw[hofs[I]] = f2bf(h); \
        int tt = dir ? (sl_s - 1 - t) : t; \
        if (tt >= 0 && ((sm_s >> tt) & 1)) mr##I = fmaxf(mr##I, h); \
    } }

#pragma unroll 1
    for (int t = 0; t < T_; ++t) {
        const int cur = t & 1, nxt = cur ^ 1;
        unsigned short* hw = (unsigned short*)&sh.hbuf[nxt][0];
        const s16x8* xb = sh.xall[t];
        s16x8 a0 = xb[laneofs];
        s16x8 a1 = xb[64 + laneofs];
        s16x8 a2 = sh.hbuf[cur][laneofs];
        s16x8 a3 = sh.hbuf[cur][64 + laneofs];

        // group 1: tiles 0,1
        {
            f32x4 d0 = {bv[0], bv[0], bv[0], bv[0]};
            f32x4 d1 = {bv[1], bv[1], bv[1], bv[1]};
            d0 = __builtin_amdgcn_mfma_f32_16x16x32_bf16(a0, bf[0][0], d0, 0, 0, 0);
            d1 = __builtin_amdgcn_mfma_f32_16x16x32_bf16(a0, bf[1][0], d1, 0, 0, 0);
            d0 = __builtin_amdgcn_mfma_f32_16x16x32_bf16(a1, bf[0][1], d0, 0, 0, 0);
            d1 = __builtin_amdgcn_mfma_f32_16x16x32_bf16(a1, bf[1][1], d1, 0, 0, 0);
            d0 = __builtin_amdgcn_mfma_f32_16x16x32_bf16(a2, bf[0][2], d0, 0, 0, 0);
            d1 = __builtin_amdgcn_mfma_f32_16x16x32_bf16(a2, bf[1][2], d1, 0, 0, 0);
            d0 = __builtin_amdgcn_mfma_f32_16x16x32_bf16(a3, bf[0][3], d0, 0, 0, 0);
            d1 = __builtin_amdgcn_mfma_f32_16x16x32_bf16(a3, bf[1][3], d1, 0, 0, 0);
            TRUPD(0, d0)
            TRUPD(1, d1)
        }
        // group 2: tiles 2 (all waves), 3 (wave 0 only)
        {
            f32x4 d2 = {bv[2], bv[2], bv[2], bv[2]};
            d2 = __builtin_amdgcn_mfma_f32_16x16x32_bf16(a0, bf[2][0], d2, 0, 0, 0);
            d2 = __builtin_amdgcn_mfma_f32_16x16x32_bf16(a1, bf[2][1], d2, 0, 0, 0);
            d2 = __builtin_amdgcn_mfma_f32_16x16x32_bf16(a2, bf[2][2], d2, 0, 0, 0);
            d2 = __builtin_amdgcn_mfma_f32_16x16x32_bf16(a3, bf[2][3], d2, 0, 0, 0);
            TRUPD(2, d2)
            if (cnt == 4) {                      // wave-uniform
                f32x4 d3 = {bv[3], bv[3], bv[3], bv[3]};
                d3 = __builtin_amdgcn_mfma_f32_16x16x32_bf16(a0, bf[3][0], d3, 0, 0, 0);
                d3 = __builtin_amdgcn_mfma_f32_16x16x32_bf16(a1, bf[3][1], d3, 0, 0, 0);
                d3 = __builtin_amdgcn_mfma_f32_16x16x32_bf16(a2, bf[3][2], d3, 0, 0, 0);
                d3 = __builtin_amdgcn_mfma_f32_16x16x32_bf16(a3, bf[3][3], d3, 0, 0, 0);
                TRUPD(3, d3)
            }
        }
        __syncthreads();   // h(t) visible for step t+1
    }

    // ---- epilogue: pooled outputs (lane owns (cell,seq) pairs) ----
    float* ob = out + (size_t)(grp * 16 + sstar) * 968 + 868 + dir * CD_;
#define OUTW(I) if (cvld[I]) { \
    float mm = mr##I; \
    if (dir && (sm_s >> sl_s)) mm = fmaxf(mm, 0.f); \
    if (mm == NEGV) mm = 0.f; \
    ob[ccol[I]] = mm; }
    OUTW(0) OUTW(1) OUTW(2) OUTW(3)
}

// ================== role B: word_reps maxpool (float4, 8-deep) + word_embed + cls ==================
__device__ void word_body(int bl, char* smem,
        const float* __restrict__ bert, const int* __restrict__ p2w,
        const int* __restrict__ word_ids, const float* __restrict__ word_table,
        float* __restrict__ out) {
    WordS& sh = *(WordS*)smem;
    int b = bl >> 7;
    int l = bl & 127;
    int tid = threadIdx.x;

    if (tid == 0) sh.cnt = 0;
    __syncthreads();
    if (tid < S_) {
        if (p2w[bl * S_ + tid]) {
            int p = atomicAdd(&sh.cnt, 1);   // order-independent: fmax is exact-commutative
            sh.list[p] = tid;
        }
    }
    __syncthreads();
    int n = sh.cnt;

    float* orow = out + (size_t)bl * 968;

    if (n > 0) {                          // n is block-uniform
        if (tid < ((8 - (n & 7)) & 7)) sh.list[n + tid] = sh.list[0];   // pad (idempotent)
        __syncthreads();
        int n8 = (n + 7) & ~7;
        if (tid < 192) {
            // threads 0..191: pool H=768 as 192 float4 columns, 8-deep load pipeline
            const float4* bb = (const float4*)(bert + (size_t)b * S_ * H_) + tid;
            float4 mx = make_float4(-FMAXV, -FMAXV, -FMAXV, -FMAXV);
            for (int i = 0; i < n8; i += 8) {
                float4 v0 = bb[(size_t)sh.list[i]     * 192];
                float4 v1 = bb[(size_t)sh.list[i + 1] * 192];
                float4 v2 = bb[(size_t)sh.list[i + 2] * 192];
                float4 v3 = bb[(size_t)sh.list[i + 3] * 192];
                float4 v4 = bb[(size_t)sh.list[i + 4] * 192];
                float4 v5 = bb[(size_t)sh.list[i + 5] * 192];
                float4 v6 = bb[(size_t)sh.list[i + 6] * 192];
                float4 v7 = bb[(size_t)sh.list[i + 7] * 192];
                mx = fmax4(mx, fmax4(fmax4(fmax4(v0, v1), fmax4(v2, v3)),
                                     fmax4(fmax4(v4, v5), fmax4(v6, v7))));
            }
            ((float4*)orow)[tid] = mx;
        } else {
            // threads 192..255: word_embed gather (concurrent with the pool loop)
            int j = tid - 192;
            int wid = word_ids[bl];
            orow[768 + j] = word_table[(size_t)wid * WD_ + j];
            if (j < WD_ - 64) orow[768 + 64 + j] = word_table[(size_t)wid * WD_ + 64 + j];
        }
    } else {
        // all-masked word (probability ~2^-160; kept for strict correctness)
        float mv = FMAXV;
        const float4* x4 = (const float4*)bert;
        for (int i = tid; i < NELEM / 4; i += 256) {
            float4 v = x4[i];
            mv = fminf(mv, fminf(fminf(v.x, v.y), fminf(v.z, v.w)));
        }
        sh.red[tid] = mv;
        __syncthreads();
        for (int o = 128; o > 0; o >>= 1) {
            if (tid < o) sh.red[tid] = fminf(sh.red[tid], sh.red[tid + o]);
            __syncthreads();
        }
        float g = sh.red[0];
        if (tid < 192) {
            ((float4*)orow)[tid] = make_float4(g, g, g, g);
        } else {
            int j = tid - 192;
            int wid = word_ids[bl];
            orow[768 + j] = word_table[(size_t)wid * WD_ + j];
            if (j < WD_ - 64) orow[768 + 64 + j] = word_table[(size_t)wid * WD_ + 64 + j];
        }
    }

    if (l == 0 && tid < 192) {   // cls embedding = bert_emb[b,0,:]
        const float4* c4 = (const float4*)(bert + (size_t)b * S_ * H_);
        float4* co = (float4*)(out + (size_t)B_ * L_ * 968 + (size_t)b * H_);
        co[tid] = c4[tid];
    }
}

// ================== mega kernel: 128 LSTM blocks first, 1024 word blocks backfill ==================
__global__ __launch_bounds__(256, 3) void kmega(
        const float* __restrict__ bert, const int* __restrict__ p2w,
        const int* __restrict__ word_ids, const int* __restrict__ char_ids,
        const int* __restrict__ char_count, const int* __restrict__ tok_mask,
        const float* __restrict__ word_table, const float* __restrict__ char_table,
        const float* __restrict__ w_ih_f, const float* __restrict__ w_hh_f,
        const float* __restrict__ b_f,
        const float* __restrict__ w_ih_b, const float* __restrict__ w_hh_b,
        const float* __restrict__ b_b,
        float* __restrict__ out) {
    __shared__ __align__(16) char smem[SMEM_BYTES];
    int bid = blockIdx.x;
    if (bid < 128) {
        lstm_body(bid, smem, char_ids, char_count, tok_mask, char_table,
                  w_ih_f, w_hh_f, b_f, w_ih_b, w_hh_b, b_b, out);
    } else {
        word_body(bid - 128, smem, bert, p2w, word_ids, word_table, out);
    }
}

extern "C" void kernel_launch(void* const* d_in, const int* in_sizes, int n_in,
                              void* d_out, int out_size, void* d_ws, size_t ws_size,
                              hipStream_t stream) {
    const float* bert       = (const float*)d_in[0];
    const int*   p2w        = (const int*)d_in[1];
    const int*   word_ids   = (const int*)d_in[2];
    const int*   char_ids   = (const int*)d_in[3];
    const int*   char_count = (const int*)d_in[4];
    const int*   tok_mask   = (const int*)d_in[5];
    const float* word_table = (const float*)d_in[6];
    const float* char_table = (const float*)d_in[7];
    const float* w_ih_f = (const float*)d_in[8];
    const float* w_hh_f = (const float*)d_in[9];
    const float* b_f    = (const float*)d_in[10];
    const float* w_ih_b = (const float*)d_in[11];
    const float* w_hh_b = (const float*)d_in[12];
    const float* b_b    = (const float*)d_in[13];

    float* out = (float*)d_out;

    kmega<<<128 + B_ * L_, 256, 0, stream>>>(bert, p2w, word_ids, char_ids, char_count, tok_mask,
                                             word_table, char_table,
                                             w_ih_f, w_hh_f, b_f, w_ih_b, w_hh_b, b_b, out);
}